// Round 11
// baseline (70.931 us; speedup 1.0000x reference)
//
#include <hip/hip_runtime.h>

// GraphConv: out[b,i,c] = relu( VW[b,0,i,c] + sum_{j,l} A[b,i,j,l] * VW[b,l+1,j,c] )
// VW[b,l,j,c] = sum_f V[b,j,f] h[l,c,f]
// K2 key fact: flattening A's (j,l) axes gives contiguous K=4096 with k=j*4+l.
// R11 K2: BM=256 x BN=256 x BK=64, KT=8, 1024 thr (16 waves 4x4, wave 64x64).
// B-traffic halves (W2t read 4x not 8x). A reg-staged 2-bank; B via glds
// (pre-swizzled source, linear dest). One fence per tile: lgkmcnt(0) +
// counted vmcnt(4) (A(t+2) stays in flight). glds B(t+1) issued only after
// the barrier that retired its buffer's readers (no race). LDS 128KB.

typedef float          f32x4  __attribute__((ext_vector_type(4)));
typedef __bf16         bf16x8 __attribute__((ext_vector_type(8)));
typedef unsigned short u16x4  __attribute__((ext_vector_type(4)));
typedef unsigned int   u32x4  __attribute__((ext_vector_type(4)));

#define DEV __device__ __forceinline__

DEV void glds16(const void* g, void* l) {
  __builtin_amdgcn_global_load_lds((const __attribute__((address_space(1))) void*)g,
                                   (__attribute__((address_space(3))) void*)l,
                                   16, 0, 0);
}

DEV void cvt8(__bf16* d, f32x4 u, f32x4 v) {
  bf16x8 o;
  o[0]=(__bf16)u[0]; o[1]=(__bf16)u[1]; o[2]=(__bf16)u[2]; o[3]=(__bf16)u[3];
  o[4]=(__bf16)v[0]; o[5]=(__bf16)v[1]; o[6]=(__bf16)v[2]; o[7]=(__bf16)v[3];
  *(bf16x8*)d = o;
}

DEV bf16x8 cvt8r(f32x4 u, f32x4 v) {
  bf16x8 o;
  o[0]=(__bf16)u[0]; o[1]=(__bf16)u[1]; o[2]=(__bf16)u[2]; o[3]=(__bf16)u[3];
  o[4]=(__bf16)v[0]; o[5]=(__bf16)v[1]; o[6]=(__bf16)v[2]; o[7]=(__bf16)v[3];
  return o;
}

DEV unsigned short bfbits(float x) {
  return __builtin_bit_cast(unsigned short, (__bf16)x);
}

// ---------------------------------------------------------------------------
// K1: VW projection.  Per block: (b, j-tile 128, c-tile 64), all 5 l.
// Writes W2t[b][c][j*4 + (l-1)] bf16 and VW0[b][j][c] f32.  (unchanged)
// ---------------------------------------------------------------------------
__global__ __launch_bounds__(512, 2)
void k1_vw(const float* __restrict__ Vg, const float* __restrict__ Hg,
           unsigned short* __restrict__ W2t, float* __restrict__ VW0)
{
  __shared__ __attribute__((aligned(16))) __bf16 Vs[2][128*64];
  __shared__ __attribute__((aligned(16))) __bf16 Hs[2][320*64];

  const int tid  = threadIdx.x;
  const int lane = tid & 63;
  const int wid  = tid >> 6;
  const int wj   = wid >> 1;
  const int wc   = wid & 1;
  const int li   = lane & 15;
  const int lg   = lane >> 4;

  const int p    = blockIdx.x;       // 256 blocks; b == XCD id
  const int b    = p & 7;
  const int rest = p >> 3;
  const int ct   = rest & 3;
  const int jt   = rest >> 2;
  const int j0   = jt * 128;
  const int c0   = ct * 64;

  const float* sptr[7];
  int sdst[7];
#pragma unroll
  for (int r = 0; r < 2; ++r) {
    int n = r*512 + tid, row = n >> 3, q = n & 7;
    sptr[r] = Vg + (size_t)(b*1024 + j0 + row)*256 + q*8;
    sdst[r] = row*64 + ((q ^ (row & 7))*8);
  }
#pragma unroll
  for (int r = 0; r < 5; ++r) {
    int n = r*512 + tid, row = n >> 3, q = n & 7;
    int l = row >> 6, cl = row & 63;
    sptr[2+r] = Hg + (size_t)(l*256 + c0 + cl)*256 + q*8;
    sdst[2+r] = row*64 + ((q ^ (row & 7))*8);
  }

  f32x4 acc[5][2][2];
#pragma unroll
  for (int l=0;l<5;l++)
#pragma unroll
    for (int x=0;x<2;x++)
#pragma unroll
      for (int y=0;y<2;y++) acc[l][x][y] = (f32x4){0.f,0.f,0.f,0.f};

  {
    f32x4 sa[14];
#pragma unroll
    for (int i=0;i<7;i++) { sa[2*i] = *(const f32x4*)(sptr[i]); sa[2*i+1] = *(const f32x4*)(sptr[i]+4); }
#pragma unroll
    for (int i=0;i<7;i++) {
      __bf16* d = (i < 2) ? &Vs[0][sdst[i]] : &Hs[0][sdst[i]];
      cvt8(d, sa[2*i], sa[2*i+1]);
    }
  }
  __syncthreads();

  int cur = 0;
#pragma unroll 1
  for (int t = 0; t < 4; ++t) {
    const int nxt = cur ^ 1;
    f32x4 sa[14];
    if (t < 3) {
      const int ko = (t+1)*64;
#pragma unroll
      for (int i=0;i<7;i++) { sa[2*i] = *(const f32x4*)(sptr[i]+ko); sa[2*i+1] = *(const f32x4*)(sptr[i]+ko+4); }
    }
    const __bf16* Vsc = &Vs[cur][0];
    const __bf16* Hsc = &Hs[cur][0];
#pragma unroll
    for (int ks = 0; ks < 2; ++ks) {
      bf16x8 hf[10], vf[2];
#pragma unroll
      for (int l=0;l<5;l++)
#pragma unroll
        for (int cm=0;cm<2;cm++) {
          int row = l*64 + wc*32 + cm*16 + li;
          int ch  = (ks*4 + lg) ^ (row & 7);
          hf[l*2+cm] = *(const bf16x8*)(Hsc + row*64 + ch*8);
        }
#pragma unroll
      for (int jn=0;jn<2;jn++) {
        int row = wj*32 + jn*16 + li;
        int ch  = (ks*4 + lg) ^ (row & 7);
        vf[jn] = *(const bf16x8*)(Vsc + row*64 + ch*8);
      }
#pragma unroll
      for (int l=0;l<5;l++)
#pragma unroll
        for (int cm=0;cm<2;cm++)
#pragma unroll
          for (int jn=0;jn<2;jn++)
            acc[l][cm][jn] = __builtin_amdgcn_mfma_f32_16x16x32_bf16(
                hf[l*2+cm], vf[jn], acc[l][cm][jn], 0, 0, 0);
    }
    if (t < 3) {
#pragma unroll
      for (int i=0;i<7;i++) {
        __bf16* d = (i < 2) ? &Vs[nxt][sdst[i]] : &Hs[nxt][sdst[i]];
        cvt8(d, sa[2*i], sa[2*i+1]);
      }
    }
    __syncthreads();
    cur = nxt;
  }

#pragma unroll
  for (int cm=0;cm<2;cm++)
#pragma unroll
    for (int r=0;r<4;r++) {
      const int c = c0 + wc*32 + cm*16 + lg*4 + r;
#pragma unroll
      for (int jn=0;jn<2;jn++) {
        const int j = j0 + wj*32 + jn*16 + li;
        u16x4 pk;
        pk[0] = bfbits(acc[1][cm][jn][r]);
        pk[1] = bfbits(acc[2][cm][jn][r]);
        pk[2] = bfbits(acc[3][cm][jn][r]);
        pk[3] = bfbits(acc[4][cm][jn][r]);
        *(u16x4*)(W2t + (size_t)(b*256 + c)*4096 + (size_t)j*4) = pk;
        VW0[(size_t)(b*1024 + j)*256 + c] = acc[0][cm][jn][r];
      }
    }
}

// ---------------------------------------------------------------------------
// K2 (R11). partial[kt][b][i][c] = sum_{k in 512-chunk} A[b][i][k]*W2t[b][c][k]
// BM=256, BN=256, BK=64, KT=8, 1024 thr = 16 waves (wi 0..3 x wc 0..3),
// wave 64i x 64c = 4x4 frags, 32 MFMA/tile, 8 tiles.
// Swizzle invariant (both operands): LDS chunk position p holds global chunk
// p ^ (row&7); read of global chunk g is at position g ^ (row&7).
// ---------------------------------------------------------------------------
__global__ __launch_bounds__(1024, 4)
void k2_gemm(const float* __restrict__ Ag, const unsigned short* __restrict__ W2t,
             unsigned short* __restrict__ part)
{
  __shared__ __attribute__((aligned(16))) __bf16 As[2][256*64];  // 2 x 32 KB
  __shared__ __attribute__((aligned(16))) __bf16 Bs[2][256*64];  // 2 x 32 KB

  const int tid  = threadIdx.x;
  const int lane = tid & 63;
  const int wid  = tid >> 6;   // 0..15
  const int wi   = wid >> 2;   // 0..3 (i 64-strips)
  const int wc   = wid & 3;    // 0..3 (c 64-strips)
  const int li   = lane & 15;
  const int lg   = lane >> 4;
  const int ls   = li & 7;     // read-side swizzle key

  const int p    = blockIdx.x;       // 256 blocks; b == XCD id
  const int b    = p & 7;
  const int rest = p >> 3;           // 0..31
  const int kt   = rest & 7;
  const int it   = rest >> 3;        // 0..3

  const int i0 = it*256;
  const int k0 = kt*512;             // element offset in K

  // ---- A staging map: ar = tid>>2 (0..255), chunks {aq, aq+4} of 8/row ----
  const int ar = tid >> 2, aq = tid & 3, as_ = ar & 7;
  const float* asrc = Ag + (size_t)(b*1024 + i0 + ar)*4096 + k0;
  const int awo0 = ar*64 + ((aq     ^ as_)*8);
  const int awo1 = ar*64 + (((aq+4) ^ as_)*8);
  const int ago0 = aq*8;
  const int ago1 = aq*8 + 32;

  // ---- B staging via glds: 2 rounds; chunk n=r*1024+tid: row=n>>3, q=n&7 ----
  const int brow = tid >> 3, bq = tid & 7, bs_ = brow & 7;
  const unsigned short* bsrc0 = W2t + (size_t)(b*256 +       brow)*4096 + k0 + ((bq ^ bs_)*8);
  const unsigned short* bsrc1 = W2t + (size_t)(b*256 + 128 + brow)*4096 + k0 + ((bq ^ bs_)*8);
  const int bd0 = wid*512;           // wave-uniform base (elems); HW adds lane*16B
  const int bd1 = 8192 + wid*512;

  f32x4 acc[4][4];
#pragma unroll
  for (int m=0;m<4;m++)
#pragma unroll
    for (int n=0;n<4;n++) acc[m][n] = (f32x4){0.f,0.f,0.f,0.f};

  // A register banks (E = even tiles, O = odd tiles)
  f32x4 aE0,aE1,aE2,aE3, aO0,aO1,aO2,aO3;

#define K2_LOADA(S, t) do {                                                  \
    const float* _ap = asrc + (t)*64;                                        \
    a##S##0 = *(const f32x4*)(_ap + ago0);                                   \
    a##S##1 = *(const f32x4*)(_ap + ago0 + 4);                               \
    a##S##2 = *(const f32x4*)(_ap + ago1);                                   \
    a##S##3 = *(const f32x4*)(_ap + ago1 + 4);                               \
  } while (0)

#define K2_GLDSB(t, X) do {                                                  \
    glds16(bsrc0 + (t)*64, &Bs[X][bd0]);                                     \
    glds16(bsrc1 + (t)*64, &Bs[X][bd1]);                                     \
  } while (0)

#define K2_DSWA(S, X) do {                                                   \
    *(bf16x8*)(&As[X][awo0]) = cvt8r(a##S##0, a##S##1);                      \
    *(bf16x8*)(&As[X][awo1]) = cvt8r(a##S##2, a##S##3);                      \
  } while (0)

#define K2_COMP(X) do {                                                      \
    _Pragma("unroll")                                                        \
    for (int kk=0;kk<2;kk++) {                                               \
      bf16x8 af[4];                                                          \
      _Pragma("unroll")                                                      \
      for (int m=0;m<4;m++) {                                                \
        int row = wi*64 + m*16 + li;                                         \
        af[m] = *(const bf16x8*)(&As[X][row*64 + (((kk*4+lg) ^ ls)*8)]);     \
      }                                                                      \
      _Pragma("unroll")                                                      \
      for (int np=0;np<2;np++) {                                             \
        bf16x8 bf0, bf1;                                                     \
        {                                                                    \
          int row0 = wc*64 + (np*2  )*16 + li;                               \
          int row1 = wc*64 + (np*2+1)*16 + li;                               \
          bf0 = *(const bf16x8*)(&Bs[X][row0*64 + (((kk*4+lg) ^ ls)*8)]);    \
          bf1 = *(const bf16x8*)(&Bs[X][row1*64 + (((kk*4+lg) ^ ls)*8)]);    \
        }                                                                    \
        __builtin_amdgcn_s_setprio(1);                                       \
        _Pragma("unroll")                                                    \
        for (int m=0;m<4;m++) {                                              \
          acc[m][np*2  ] = __builtin_amdgcn_mfma_f32_16x16x32_bf16(          \
              af[m], bf0, acc[m][np*2  ], 0, 0, 0);                          \
          acc[m][np*2+1] = __builtin_amdgcn_mfma_f32_16x16x32_bf16(          \
              af[m], bf1, acc[m][np*2+1], 0, 0, 0);                          \
        }                                                                    \
        __builtin_amdgcn_s_setprio(0);                                       \
      }                                                                      \
    }                                                                        \
  } while (0)

#define K2_BARSB() do {                                                      \
    __builtin_amdgcn_sched_barrier(0);                                       \
    __builtin_amdgcn_s_barrier();                                            \
    __builtin_amdgcn_sched_barrier(0);                                       \
  } while (0)

  // ---- prologue: A(0)->buf0, B(0)->buf0, A(1)->bank O ----
  K2_LOADA(E, 0);
  K2_GLDSB(0, 0);
  K2_DSWA(E, 0);          // auto-waits A(0) loads (vmcnt counted past B glds)
  K2_LOADA(O, 1);
  asm volatile("s_waitcnt lgkmcnt(0)" ::: "memory");
  asm volatile("s_waitcnt vmcnt(4)"  ::: "memory");   // B(0) landed; A(1) in flight
  K2_BARSB();

  // ---- main loop: tiles 0..5 (3 x unroll-2) ----
#pragma unroll 1
  for (int u = 0; u < 3; ++u) {
    // t = 2u (even): COMP buf0
    K2_GLDSB(2*u+1, 1);   // B(t+1) -> buf1 (readers retired at last barrier)
    K2_LOADA(E, 2*u+2);   // A(t+2) -> bank E
    K2_COMP(0);
    K2_DSWA(O, 1);        // A(t+1) -> buf1 (auto vmcnt counted)
    asm volatile("s_waitcnt lgkmcnt(0)" ::: "memory");
    asm volatile("s_waitcnt vmcnt(4)"  ::: "memory"); // B(t+1) landed; A(t+2) in flight
    K2_BARSB();

    // t = 2u+1 (odd): COMP buf1
    K2_GLDSB(2*u+2, 0);   // B(t+1) -> buf0
    K2_LOADA(O, 2*u+3);   // A(t+2) -> bank O
    K2_COMP(1);
    K2_DSWA(E, 0);        // A(t+1) -> buf0
    asm volatile("s_waitcnt lgkmcnt(0)" ::: "memory");
    asm volatile("s_waitcnt vmcnt(4)"  ::: "memory");
    K2_BARSB();
  }
  // ---- t = 6: COMP buf0; stage B(7),A(7) -> buf1 ----
  K2_GLDSB(7, 1);
  K2_COMP(0);
  K2_DSWA(O, 1);
  asm volatile("s_waitcnt lgkmcnt(0)" ::: "memory");
  asm volatile("s_waitcnt vmcnt(0)"  ::: "memory");
  K2_BARSB();
  // ---- t = 7 ----
  K2_COMP(1);

#undef K2_LOADA
#undef K2_GLDSB
#undef K2_DSWA
#undef K2_COMP
#undef K2_BARSB

  // ---- epilogue -> bf16 partial plane ----
  unsigned short* pb = part + (size_t)kt*2097152u + (size_t)(b*1024 + i0)*256;
#pragma unroll
  for (int m=0;m<4;m++)
#pragma unroll
    for (int r=0;r<4;r++) {
      const int il = wi*64 + m*16 + lg*4 + r;
#pragma unroll
      for (int n=0;n<4;n++) {
        const int cl = wc*64 + n*16 + li;
        pb[(size_t)il*256 + cl] = bfbits(acc[m][n][r]);
      }
    }
}

// ---------------------------------------------------------------------------
// K3: out = relu(VW0 + sum_{kt<8} partial[kt]), 8 elems/thread.
// b == XCD id: partials/VW0 for batch b are L2-local to the producing XCD.
// ---------------------------------------------------------------------------
__global__ __launch_bounds__(256)
void k3_reduce(const unsigned short* __restrict__ part, const float* __restrict__ VW0,
               float* __restrict__ out)
{
  const int g   = blockIdx.x;        // 1024 blocks
  const int b   = g & 7;
  const int off = g >> 3;            // 0..127
  const size_t i8 = (size_t)b*262144u + (size_t)off*2048u + (size_t)threadIdx.x*8;
  f32x4 s0 = *(const f32x4*)(VW0 + i8);
  f32x4 s1 = *(const f32x4*)(VW0 + i8 + 4);
#pragma unroll
  for (int q=0;q<8;q++) {
    u32x4 u = *(const u32x4*)(part + (size_t)q*2097152u + i8);
    s0[0] += __uint_as_float(u[0] << 16);  s0[1] += __uint_as_float(u[0] & 0xffff0000u);
    s0[2] += __uint_as_float(u[1] << 16);  s0[3] += __uint_as_float(u[1] & 0xffff0000u);
    s1[0] += __uint_as_float(u[2] << 16);  s1[1] += __uint_as_float(u[2] & 0xffff0000u);
    s1[2] += __uint_as_float(u[3] << 16);  s1[3] += __uint_as_float(u[3] & 0xffff0000u);
  }
#pragma unroll
  for (int e=0;e<4;e++){ s0[e] = fmaxf(s0[e],0.f); s1[e] = fmaxf(s1[e],0.f); }
  *(f32x4*)(out + i8)     = s0;
  *(f32x4*)(out + i8 + 4) = s1;
}

// ---------------------------------------------------------------------------
extern "C" void kernel_launch(void* const* d_in, const int* in_sizes, int n_in,
                              void* d_out, int out_size, void* d_ws, size_t ws_size,
                              hipStream_t stream) {
  const float* Vg = (const float*)d_in[0];   // (8,1024,256) f32
  const float* Ag = (const float*)d_in[1];   // (8,1024,1024,4) f32
  const float* Hg = (const float*)d_in[2];   // (5,256,256) f32
  float* out = (float*)d_out;                // (8,1024,256) f32

  // ws: W2t bf16 16MB | VW0 f32 8MB | partials bf16 32MB = 56MB
  if (ws_size < 58720256u) return;
  char* ws = (char*)d_ws;
  unsigned short* W2t  = (unsigned short*)(ws);
  float*          VW0  = (float*)(ws + 16777216u);
  unsigned short* part = (unsigned short*)(ws + 16777216u + 8388608u);

  k1_vw    <<<dim3(256),  dim3(512),  0, stream>>>(Vg, Hg, W2t, VW0);
  k2_gemm  <<<dim3(256),  dim3(1024), 0, stream>>>(Ag, W2t, part);
  k3_reduce<<<dim3(1024), dim3(256),  0, stream>>>(part, VW0, out);
}